// Round 7
// baseline (1985.672 us; speedup 1.0000x reference)
//
#include <hip/hip_runtime.h>

// SwinV2 block, MI355X. GEMMs: bf16 MFMA 16x16x32, fp32 accum, BM=256 x
// BN=128, 4 waves x (64x128), BK=32, 2-deep LDS ring (48KB -> 3 blocks/CU),
// vmcnt(0)+raw barrier with one-compute-phase slack, full K-loop unroll.
// Producer-side XOR swizzle -> 0 bank conflicts. XCD-chunked n-fast grid.
// tanh-GELU epilogue; qkv output plain rows (no scatter).

typedef unsigned int uint32;
typedef unsigned short u16;
typedef __attribute__((ext_vector_type(4))) float f32x4;
typedef __attribute__((ext_vector_type(8))) __bf16 bf16x8;

static __device__ __forceinline__ u16 f2bf(float f) {
    union { float f; uint32 u; } v; v.f = f;
    uint32 r = v.u + 0x7fffu + ((v.u >> 16) & 1u);
    return (u16)(r >> 16);
}
static __device__ __forceinline__ float bf2f(u16 h) {
    union { uint32 u; float f; } v; v.u = ((uint32)h) << 16; return v.f;
}
static __device__ __forceinline__ uint32 pack2(float a, float b) {
    return (uint32)f2bf(a) | ((uint32)f2bf(b) << 16);
}
static __device__ __forceinline__ float blo(uint32 u){ union{uint32 u;float f;}v; v.u=u<<16; return v.f; }
static __device__ __forceinline__ float bhi(uint32 u){ union{uint32 u;float f;}v; v.u=u&0xffff0000u; return v.f; }

typedef __attribute__((address_space(1))) const void gas_void;
typedef __attribute__((address_space(3))) void las_void;
static __device__ __forceinline__ void glds16(const void* g, void* l) {
    __builtin_amdgcn_global_load_lds((gas_void*)g, (las_void*)l, 16, 0, 0);
}

// swizzle: XOR the 8-elem slot index with (row>>1)&3 -> 2 lanes/bank (free)
#define SWZ(c, row) ((c) ^ ((((row) >> 1) & 3) << 3))

#define VMCNT(N) asm volatile("s_waitcnt vmcnt(" #N ")" ::: "memory")
#define BARM() do { asm volatile("" ::: "memory"); __builtin_amdgcn_s_barrier(); asm volatile("" ::: "memory"); } while (0)

// tanh-form GELU: x*(1 - 1/(exp(1.5957691x + 0.0713548x^3)+1)), |err|<5e-4
static __device__ __forceinline__ float fast_gelu(float x) {
    float x2 = x * x;
    float w = x * fmaf(0.0713548162f, x2, 1.5957691216f);
    float e = __expf(w);
    float r = __builtin_amdgcn_rcpf(e + 1.0f);
    return fmaf(-x, r, x);
}

// ---------------- setup kernels ----------------

__global__ void wt_convert(const float* __restrict__ W, u16* __restrict__ WT, int K, int N) {
    long idx = (long)blockIdx.x * 256 + threadIdx.x;
    long tot = (long)K * N;
    if (idx >= tot) return;
    int n = (int)(idx / K), k = (int)(idx - (long)n * K);
    WT[(long)n * K + SWZ(k, n)] = f2bf(W[(long)k * N + n]);
}

__global__ void build_qkv_bias(const float* __restrict__ qb, const float* __restrict__ vb,
                               float* __restrict__ outb) {
    int c = blockIdx.x * 256 + threadIdx.x;
    if (c >= 1152) return;
    outb[c] = (c < 384) ? qb[c] : ((c < 768) ? 0.f : vb[c - 768]);
}

__global__ void cpb_tab(const float* __restrict__ table, const float* __restrict__ w1,
                        const float* __restrict__ b1, const float* __restrict__ w2,
                        float* __restrict__ tab) {
    __shared__ float hid[512];
    int e = blockIdx.x;
    float tx = table[e * 2 + 0], ty = table[e * 2 + 1];
    for (int u = threadIdx.x; u < 512; u += 256)
        hid[u] = fmaxf(tx * w1[u] + ty * w1[512 + u] + b1[u], 0.f);
    __syncthreads();
    if (threadIdx.x < 12) {
        float s = 0.f;
        for (int u = 0; u < 512; ++u) s += hid[u] * w2[u * 12 + threadIdx.x];
        tab[e * 12 + threadIdx.x] = s;
    }
}

__global__ void cpb_bias(const float* __restrict__ tab, const int* __restrict__ rpi,
                         float* __restrict__ bias16) {
    int idx = blockIdx.x * 256 + threadIdx.x;
    if (idx >= 12 * 144 * 144) return;
    int h = idx / 20736, ij = idx - h * 20736;
    float t = tab[rpi[ij] * 12 + h];
    bias16[idx] = 16.f / (1.f + __expf(-t));
}

__global__ void gather_xbf(const float* __restrict__ x, u16* __restrict__ xw) {
    int idx = blockIdx.x * 256 + threadIdx.x;
    if (idx >= 73728 * 48) return;
    int row = idx / 48, c = (idx - row * 48) * 8;
    int win = row / 144, n = row - win * 144;
    int b = win >> 4, wi = win & 15;
    int r = n / 12, cc = n - r * 12;
    int sh = ((wi >> 2) * 12 + r + 6) % 48;
    int sw = ((wi & 3) * 12 + cc + 6) % 48;
    long src = ((long)(b * 2304 + sh * 48 + sw)) * 384 + c;
    float4 f0 = *(const float4*)(x + src);
    float4 f1 = *(const float4*)(x + src + 4);
    uint4 o;
    o.x = pack2(f0.x, f0.y); o.y = pack2(f0.z, f0.w);
    o.z = pack2(f1.x, f1.y); o.w = pack2(f1.z, f1.w);
    *(uint4*)(xw + (long)row * 384 + SWZ(c, row)) = o;
}

// ---------------- GEMM ----------------

enum { EPI_PLAIN = 1, EPI_GELU = 2 };

template<int EPI, bool OSWZ, int NK>
__global__ __launch_bounds__(256, 3) void gemm_k(
    const u16* __restrict__ Ag, const u16* __restrict__ Bg,
    const float* __restrict__ bias, u16* __restrict__ outp,
    int N, int ntn)
{
    constexpr int K = NK * 32;
    __shared__ __align__(16) u16 As[2][8192];   // 256 x 32 per buf
    __shared__ __align__(16) u16 Bs[2][4096];   // 128 x 32 per buf

    const int tid = threadIdx.x, lane = tid & 63, wid = tid >> 6;
    const int qq = gridDim.x >> 3;
    const int wg = (blockIdx.x & 7) * qq + (blockIdx.x >> 3);
    const int mIdx = wg / ntn, nIdx = wg - mIdx * ntn;
    const int m0 = mIdx << 8, n0 = nIdx << 7;

    const int wrow = wid << 6;            // per-wave 64 rows x all 128 cols
    const int fr = lane & 15, gsel = lane >> 4;

    // staging: one glds16 = 64 lanes x 16B = 16 rows x 32 cols
    const int srow = (wid << 4) + (lane >> 2);
    const int scol = (lane & 3) << 3;
    const u16* aP[4];
    const u16* bP[2];
#pragma unroll
    for (int q = 0; q < 4; ++q) aP[q] = Ag + (long)(m0 + (q << 6) + srow) * K + scol;
#pragma unroll
    for (int q = 0; q < 2; ++q) bP[q] = Bg + (long)(n0 + (q << 6) + srow) * K + scol;

    auto stage = [&](int buf, int kt) {
#pragma unroll
        for (int q = 0; q < 4; ++q)
            glds16(aP[q] + (kt << 5), &As[buf][((q << 6) + (wid << 4)) * 32]);
#pragma unroll
        for (int q = 0; q < 2; ++q)
            glds16(bP[q] + (kt << 5), &Bs[buf][((q << 6) + (wid << 4)) * 32]);
    };

    int arow[4], acol[4], brow[8], bcol[8];
#pragma unroll
    for (int i = 0; i < 4; ++i) {
        arow[i] = wrow + i * 16 + fr;
        acol[i] = (gsel ^ ((arow[i] >> 1) & 3)) << 3;
    }
#pragma unroll
    for (int j = 0; j < 8; ++j) {
        brow[j] = j * 16 + fr;
        bcol[j] = (gsel ^ ((brow[j] >> 1) & 3)) << 3;
    }

    f32x4 acc[4][8];
    const f32x4 zero4 = {0.f, 0.f, 0.f, 0.f};
#pragma unroll
    for (int i = 0; i < 4; ++i)
#pragma unroll
        for (int j = 0; j < 8; ++j) acc[i][j] = zero4;

    auto compute = [&](int buf) {
        const u16* pa = &As[buf][0];
        const u16* pb = &Bs[buf][0];
        bf16x8 af[4], bg[8];
#pragma unroll
        for (int i = 0; i < 4; ++i) af[i] = *(const bf16x8*)&pa[arow[i] * 32 + acol[i]];
#pragma unroll
        for (int j = 0; j < 8; ++j) bg[j] = *(const bf16x8*)&pb[brow[j] * 32 + bcol[j]];
#pragma unroll
        for (int i = 0; i < 4; ++i)
#pragma unroll
            for (int j = 0; j < 8; ++j)
                acc[i][j] = __builtin_amdgcn_mfma_f32_16x16x32_bf16(af[i], bg[j], acc[i][j], 0, 0, 0);
    };

    // 2-deep pipeline: loads for tile k are issued one full compute phase
    // before the vmcnt(0)+barrier that publishes them (slack ~1900 cyc).
    stage(0, 0);
#pragma unroll
    for (int g = 0; g < NK / 2; ++g) {
        VMCNT(0); BARM();
        stage(1, 2 * g + 1);
        compute(0);
        VMCNT(0); BARM();
        if (g + 1 < NK / 2) stage(0, 2 * g + 2);
        compute(1);
    }

    // ---------------- epilogue ----------------
    const int rbase = gsel << 2;
    float bv[8];
#pragma unroll
    for (int j = 0; j < 8; ++j) bv[j] = bias[n0 + j * 16 + fr];
#pragma unroll
    for (int i = 0; i < 4; ++i) {
#pragma unroll
        for (int r = 0; r < 4; ++r) {
            const int gm = m0 + wrow + i * 16 + rbase + r;
            u16* orow = outp + (long)gm * N;
            const int sx = OSWZ ? (((gm >> 1) & 3) << 3) : 0;
#pragma unroll
            for (int j = 0; j < 8; ++j) {
                const int gn = n0 + j * 16 + fr;
                float v = acc[i][j][r] + bv[j];
                if constexpr (EPI == EPI_GELU) v = fast_gelu(v);
                orow[gn ^ sx] = f2bf(v);
            }
        }
    }
}

// ---------------- attention: one (window, head) per block, 3 waves ----------------

__global__ __launch_bounds__(192) void attn_k(
    const u16* __restrict__ qkv,      // [73728][1152] bf16, plain rows
    const float* __restrict__ bias16, // [12][144][144]
    const float* __restrict__ mask,   // [16][144][144]
    const float* __restrict__ lsc,    // [12]
    u16* __restrict__ attn_o)         // [73728][384] bf16, swizzled cols
{
    __shared__ __align__(16) u16 KL[144][40];
    __shared__ __align__(16) u16 VT[32][168];
    __shared__ __align__(16) u16 PL[3][16][168];
    const int blk = blockIdx.x;
    const int win = blk / 12, head = blk - win * 12;
    const int tid = threadIdx.x, lane = tid & 63, wid = tid >> 6;
    const u16* Qp = qkv + (long)win * 144 * 1152 + head * 32;
    const u16* Kp = Qp + 384;
    const u16* Vp = Qp + 768;
    const float scale = __expf(fminf(lsc[head], 4.6051701859880914f));

    if (tid < 144) {
        const uint4* s = (const uint4*)(Kp + (long)tid * 1152);
        uint4 uu[4] = { s[0], s[1], s[2], s[3] };
        float f[32];
#pragma unroll
        for (int q = 0; q < 4; ++q) {
            f[q*8+0]=blo(uu[q].x); f[q*8+1]=bhi(uu[q].x);
            f[q*8+2]=blo(uu[q].y); f[q*8+3]=bhi(uu[q].y);
            f[q*8+4]=blo(uu[q].z); f[q*8+5]=bhi(uu[q].z);
            f[q*8+6]=blo(uu[q].w); f[q*8+7]=bhi(uu[q].w);
        }
        float ss = 0.f;
#pragma unroll
        for (int i = 0; i < 32; ++i) ss += f[i] * f[i];
        float inv = 1.f / fmaxf(sqrtf(ss), 1e-12f);
        uint32 pk[16];
#pragma unroll
        for (int i = 0; i < 16; ++i) pk[i] = pack2(f[2*i] * inv, f[2*i+1] * inv);
        uint4* d = (uint4*)&KL[tid][0];
        d[0] = make_uint4(pk[0], pk[1], pk[2], pk[3]);
        d[1] = make_uint4(pk[4], pk[5], pk[6], pk[7]);
        d[2] = make_uint4(pk[8], pk[9], pk[10], pk[11]);
        d[3] = make_uint4(pk[12], pk[13], pk[14], pk[15]);
        const uint4* sv = (const uint4*)(Vp + (long)tid * 1152);
        uint4 vv[4] = { sv[0], sv[1], sv[2], sv[3] };
        u16 vs[32];
#pragma unroll
        for (int q = 0; q < 4; ++q) {
            vs[q*8+0] = (u16)(vv[q].x & 0xffffu); vs[q*8+1] = (u16)(vv[q].x >> 16);
            vs[q*8+2] = (u16)(vv[q].y & 0xffffu); vs[q*8+3] = (u16)(vv[q].y >> 16);
            vs[q*8+4] = (u16)(vv[q].z & 0xffffu); vs[q*8+5] = (u16)(vv[q].z >> 16);
            vs[q*8+6] = (u16)(vv[q].w & 0xffffu); vs[q*8+7] = (u16)(vv[q].w >> 16);
        }
#pragma unroll
        for (int d2 = 0; d2 < 32; ++d2) VT[d2][tid] = vs[d2];
    }
    for (int idx = tid; idx < 512; idx += 192) VT[idx >> 4][144 + (idx & 15)] = 0;
    __syncthreads();

    const int fr = lane & 15, fk = (lane >> 4) << 3, rb = (lane >> 4) << 2;
    const int wim = win & 15;
    const f32x4 zero4 = {0.f, 0.f, 0.f, 0.f};

    for (int s = wid; s < 9; s += 3) {
        const uint4 qu = *(const uint4*)(Qp + (long)(s * 16 + fr) * 1152 + fk);
        float qf[8];
        qf[0]=blo(qu.x); qf[1]=bhi(qu.x); qf[2]=blo(qu.y); qf[3]=bhi(qu.y);
        qf[4]=blo(qu.z); qf[5]=bhi(qu.z); qf[6]=blo(qu.w); qf[7]=bhi(qu.w);
        float ss = 0.f;
#pragma unroll
        for (int i = 0; i < 8; ++i) ss += qf[i] * qf[i];
        ss += __shfl_xor(ss, 16);
        ss += __shfl_xor(ss, 32);
        float qinv = scale / fmaxf(sqrtf(ss), 1e-12f);
        union { uint32 u[4]; bf16x8 v; } cv;
#pragma unroll
        for (int i = 0; i < 4; ++i) cv.u[i] = pack2(qf[2*i] * qinv, qf[2*i+1] * qinv);
        bf16x8 aq = cv.v;

        f32x4 sacc[9];
#pragma unroll
        for (int jt = 0; jt < 9; ++jt) sacc[jt] = zero4;
#pragma unroll
        for (int jt = 0; jt < 9; ++jt) {
            bf16x8 bk = *(const bf16x8*)&KL[jt * 16 + fr][fk];
            sacc[jt] = __builtin_amdgcn_mfma_f32_16x16x32_bf16(aq, bk, sacc[jt], 0, 0, 0);
        }
        float mx[4] = {-1e30f, -1e30f, -1e30f, -1e30f};
#pragma unroll
        for (int jt = 0; jt < 9; ++jt) {
            int gj = jt * 16 + fr;
#pragma unroll
            for (int r = 0; r < 4; ++r) {
                int gi = s * 16 + rb + r;
                float v = sacc[jt][r] + bias16[(head * 144 + gi) * 144 + gj]
                                      + mask[(wim * 144 + gi) * 144 + gj];
                sacc[jt][r] = v;
                mx[r] = fmaxf(mx[r], v);
            }
        }
#pragma unroll
        for (int r = 0; r < 4; ++r) {
#pragma unroll
            for (int o = 1; o < 16; o <<= 1) mx[r] = fmaxf(mx[r], __shfl_xor(mx[r], o));
        }
        float sm[4] = {0.f, 0.f, 0.f, 0.f};
#pragma unroll
        for (int jt = 0; jt < 9; ++jt)
#pragma unroll
            for (int r = 0; r < 4; ++r) {
                float e = __expf(sacc[jt][r] - mx[r]);
                sacc[jt][r] = e;
                sm[r] += e;
            }
#pragma unroll
        for (int r = 0; r < 4; ++r) {
#pragma unroll
            for (int o = 1; o < 16; o <<= 1) sm[r] += __shfl_xor(sm[r], o);
            sm[r] = 1.f / sm[r];
        }
#pragma unroll
        for (int jt = 0; jt < 9; ++jt)
#pragma unroll
            for (int r = 0; r < 4; ++r)
                PL[wid][rb + r][jt * 16 + fr] = f2bf(sacc[jt][r]);
#pragma unroll
        for (int r = 0; r < 4; ++r) PL[wid][rb + r][144 + fr] = 0;

        f32x4 oa0 = zero4, oa1 = zero4;
#pragma unroll
        for (int kt = 0; kt < 5; ++kt) {
            bf16x8 ap  = *(const bf16x8*)&PL[wid][fr][kt * 32 + fk];
            bf16x8 bv0 = *(const bf16x8*)&VT[fr][kt * 32 + fk];
            bf16x8 bv1 = *(const bf16x8*)&VT[16 + fr][kt * 32 + fk];
            oa0 = __builtin_amdgcn_mfma_f32_16x16x32_bf16(ap, bv0, oa0, 0, 0, 0);
            oa1 = __builtin_amdgcn_mfma_f32_16x16x32_bf16(ap, bv1, oa1, 0, 0, 0);
        }
#pragma unroll
        for (int r = 0; r < 4; ++r) {
            long row = (long)win * 144 + s * 16 + rb + r;
            int c0 = head * 32 + fr, c1 = head * 32 + 16 + fr;
            attn_o[row * 384 + SWZ(c0, row)] = f2bf(oa0[r] * sm[r]);
            attn_o[row * 384 + SWZ(c1, row)] = f2bf(oa1[r] * sm[r]);
        }
    }
}

// ---------------- LayerNorm + residual (vectorized lanes) ----------------

__global__ __launch_bounds__(256) void ln1_k(
    const u16* __restrict__ pin, const float* __restrict__ x,
    const float* __restrict__ g, const float* __restrict__ bb,
    u16* __restrict__ y1b)
{
    const int token = blockIdx.x * 4 + (threadIdx.x >> 6);
    const int lane = threadIdx.x & 63;
    int b = token / 2304, hw = token - b * 2304;
    int h = hw / 48, w = hw - h * 48;
    int sh = h + 42; if (sh >= 48) sh -= 48;
    int sw = w + 42; if (sw >= 48) sw -= 48;
    int wh = sh / 12, r = sh - wh * 12;
    int ww = sw / 12, cc = sw - ww * 12;
    long srow = (long)(b * 16 + wh * 4 + ww) * 144 + r * 12 + cc;
    const u16* src = pin + srow * 384;
    const int c0 = lane * 4, c1 = 256 + lane * 2;
    uint2 p0 = *(const uint2*)(src + c0);
    uint32 p1 = *(const uint32*)(src + c1);
    float v[6] = { blo(p0.x), bhi(p0.x), blo(p0.y), bhi(p0.y), blo(p1), bhi(p1) };
    float s1 = 0.f, s2 = 0.f;
#pragma unroll
    for (int i = 0; i < 6; ++i) { s1 += v[i]; s2 += v[i] * v[i]; }
#pragma unroll
    for (int o = 1; o < 64; o <<= 1) { s1 += __shfl_xor(s1, o); s2 += __shfl_xor(s2, o); }
    float mean = s1 * (1.f / 384.f);
    float var = s2 * (1.f / 384.f) - mean * mean;
    float rs = rsqrtf(var + 1e-5f);
    const float* xx = x + (long)token * 384;
    float4 r0 = *(const float4*)(xx + c0);
    float2 r1 = *(const float2*)(xx + c1);
    float4 g0 = *(const float4*)(g + c0);
    float2 g1 = *(const float2*)(g + c1);
    float4 b0 = *(const float4*)(bb + c0);
    float2 b1 = *(const float2*)(bb + c1);
    float o0 = r0.x + (v[0] - mean) * rs * g0.x + b0.x;
    float o1 = r0.y + (v[1] - mean) * rs * g0.y + b0.y;
    float o2 = r0.z + (v[2] - mean) * rs * g0.z + b0.z;
    float o3 = r0.w + (v[3] - mean) * rs * g0.w + b0.w;
    float o4 = r1.x + (v[4] - mean) * rs * g1.x + b1.x;
    float o5 = r1.y + (v[5] - mean) * rs * g1.y + b1.y;
    u16* oo = y1b + (long)token * 384;
    const int sx = ((token >> 1) & 3) << 3;
    uint2 w0; w0.x = pack2(o0, o1); w0.y = pack2(o2, o3);
    *(uint2*)(oo + (c0 ^ sx)) = w0;
    *(uint32*)(oo + (c1 ^ sx)) = pack2(o4, o5);
}

__global__ __launch_bounds__(256) void ln2_k(
    const u16* __restrict__ t2, const u16* __restrict__ y1b,
    const float* __restrict__ g, const float* __restrict__ bb,
    float* __restrict__ outp)
{
    const int token = blockIdx.x * 4 + (threadIdx.x >> 6);
    const int lane = threadIdx.x & 63;
    const int c0 = lane * 4, c1 = 256 + lane * 2;
    const u16* src = t2 + (long)token * 384;
    uint2 p0 = *(const uint2*)(src + c0);
    uint32 p1 = *(const uint32*)(src + c1);
    float v[6] = { blo(p0.x), bhi(p0.x), blo(p0.y), bhi(p0.y), blo(p1), bhi(p1) };
    float s1 = 0.f, s2 = 0.f;
#pragma unroll
    for (int i = 0; i < 6; ++i) { s1 += v[i]; s2 += v[i] * v[i]; }
#pragma unroll
    for (int o = 1; o < 64; o <<= 1) { s1 += __shfl_xor(s1, o); s2 += __shfl_xor(s2, o); }
    float mean = s1 * (1.f / 384.f);
    float var = s2 * (1.f / 384.f) - mean * mean;
    float rs = rsqrtf(var + 1e-5f);
    const u16* rr = y1b + (long)token * 384;
    const int sx = ((token >> 1) & 3) << 3;
    uint2 q0 = *(const uint2*)(rr + (c0 ^ sx));
    uint32 q1 = *(const uint32*)(rr + (c1 ^ sx));
    float4 g0 = *(const float4*)(g + c0);
    float2 g1 = *(const float2*)(g + c1);
    float4 b0 = *(const float4*)(bb + c0);
    float2 b1 = *(const float2*)(bb + c1);
    float* oo = outp + (long)token * 384;
    float4 w0;
    w0.x = blo(q0.x) + (v[0] - mean) * rs * g0.x + b0.x;
    w0.y = bhi(q0.x) + (v[1] - mean) * rs * g0.y + b0.y;
    w0.z = blo(q0.y) + (v[2] - mean) * rs * g0.z + b0.z;
    w0.w = bhi(q0.y) + (v[3] - mean) * rs * g0.w + b0.w;
    float2 w1;
    w1.x = blo(q1) + (v[4] - mean) * rs * g1.x + b1.x;
    w1.y = bhi(q1) + (v[5] - mean) * rs * g1.y + b1.y;
    *(float4*)(oo + c0) = w0;
    *(float2*)(oo + c1) = w1;
}

// ---------------- launch ----------------

extern "C" void kernel_launch(void* const* d_in, const int* in_sizes, int n_in,
                              void* d_out, int out_size, void* d_ws, size_t ws_size,
                              hipStream_t stream) {
    (void)in_sizes; (void)n_in; (void)out_size; (void)ws_size;
    const float* x      = (const float*)d_in[0];
    const float* table  = (const float*)d_in[1];
    const int*   rpi    = (const int*)d_in[2];
    const float* mask   = (const float*)d_in[3];
    const float* qkv_w  = (const float*)d_in[4];
    const float* q_bias = (const float*)d_in[5];
    const float* v_bias = (const float*)d_in[6];
    const float* lsc    = (const float*)d_in[7];
    const float* cpb_w1 = (const float*)d_in[8];
    const float* cpb_b1 = (const float*)d_in[9];
    const float* cpb_w2 = (const float*)d_in[10];
    const float* proj_w = (const float*)d_in[11];
    const float* proj_b = (const float*)d_in[12];
    const float* n1g    = (const float*)d_in[13];
    const float* n1b    = (const float*)d_in[14];
    const float* n2g    = (const float*)d_in[15];
    const float* n2b    = (const float*)d_in[16];
    const float* fc1_w  = (const float*)d_in[17];
    const float* fc1_b  = (const float*)d_in[18];
    const float* fc2_w  = (const float*)d_in[19];
    const float* fc2_b  = (const float*)d_in[20];
    float* outp = (float*)d_out;

    char* ws = (char*)d_ws;
    const size_t offA    = 0;                       // qkvb(170MB) -> proj_o -> hbuf(226MB)
    const size_t offB    = 226492416;               // attn_o -> t2 (56.6MB)
    const size_t offC    = offB + 56623104;         // xw -> y1b (56.6MB)
    const size_t offBias = offC + 56623104;
    const size_t offTab  = offBias + 995328;
    const size_t offQW   = offTab + 25600;
    const size_t offPW   = offQW + 884736;
    const size_t offF1   = offPW + 294912;
    const size_t offF2   = offF1 + 1179648;
    const size_t offQB   = offF2 + 1179648;

    u16*   qkvb    = (u16*)(ws + offA);
    u16*   proj_o  = (u16*)(ws + offA);
    u16*   hbuf    = (u16*)(ws + offA);
    u16*   attn_o  = (u16*)(ws + offB);
    u16*   t2      = (u16*)(ws + offB);
    u16*   xw      = (u16*)(ws + offC);
    u16*   y1b     = (u16*)(ws + offC);
    float* bias16  = (float*)(ws + offBias);
    float* tab     = (float*)(ws + offTab);
    u16*   qkv_wT  = (u16*)(ws + offQW);
    u16*   proj_wT = (u16*)(ws + offPW);
    u16*   fc1_wT  = (u16*)(ws + offF1);
    u16*   fc2_wT  = (u16*)(ws + offF2);
    float* qkvbias = (float*)(ws + offQB);

    wt_convert<<<(384 * 1152 + 255) / 256, 256, 0, stream>>>(qkv_w, qkv_wT, 384, 1152);
    wt_convert<<<(384 * 384 + 255) / 256, 256, 0, stream>>>(proj_w, proj_wT, 384, 384);
    wt_convert<<<(384 * 1536 + 255) / 256, 256, 0, stream>>>(fc1_w, fc1_wT, 384, 1536);
    wt_convert<<<(1536 * 384 + 255) / 256, 256, 0, stream>>>(fc2_w, fc2_wT, 1536, 384);
    build_qkv_bias<<<5, 256, 0, stream>>>(q_bias, v_bias, qkvbias);
    cpb_tab<<<529, 256, 0, stream>>>(table, cpb_w1, cpb_b1, cpb_w2, tab);
    cpb_bias<<<(12 * 144 * 144 + 255) / 256, 256, 0, stream>>>(tab, rpi, bias16);
    gather_xbf<<<(73728 * 48 + 255) / 256, 256, 0, stream>>>(x, xw);

    // qkv: plain [73728][1152]
    gemm_k<EPI_PLAIN, false, 12><<<288 * 9, 256, 0, stream>>>(xw, qkv_wT, qkvbias, qkvb, 1152, 9);

    attn_k<<<6144, 192, 0, stream>>>(qkvb, bias16, mask, lsc, attn_o);

    gemm_k<EPI_PLAIN, false, 12><<<288 * 3, 256, 0, stream>>>(attn_o, proj_wT, proj_b, proj_o, 384, 3);

    ln1_k<<<18432, 256, 0, stream>>>(proj_o, x, n1g, n1b, y1b);

    gemm_k<EPI_GELU, true, 12><<<288 * 12, 256, 0, stream>>>(y1b, fc1_wT, fc1_b, hbuf, 1536, 12);

    gemm_k<EPI_PLAIN, false, 48><<<288 * 3, 256, 0, stream>>>(hbuf, fc2_wT, fc2_b, t2, 384, 3);

    ln2_k<<<18432, 256, 0, stream>>>(t2, y1b, n2g, n2b, outp);
}

// Round 8
// 721.594 us; speedup vs baseline: 2.7518x; 2.7518x over previous
//
#include <hip/hip_runtime.h>

// SwinV2 block, MI355X. GEMMs: bf16 MFMA 16x16x32, fp32 accum, BM=256 x
// BN=128, 4 waves x (64x128), BK=32, 3-deep ring LDS (72KB dynamic) with
// STATIC buffer indices + counted vmcnt(6) + raw s_barrier.
// __launch_bounds__(256,2): VGPR budget 256 -> NO spill (round-7 lesson:
// (256,3) spilled the 128-reg accumulator to scratch, 1.8GB HBM traffic).
// Producer-side XOR swizzle -> 0 bank conflicts. XCD-chunked n-fast grid.
// Plain qkv rows (no scatter epilogue); tanh-GELU; vectorized LNs.

typedef unsigned int uint32;
typedef unsigned short u16;
typedef __attribute__((ext_vector_type(4))) float f32x4;
typedef __attribute__((ext_vector_type(8))) __bf16 bf16x8;

static __device__ __forceinline__ u16 f2bf(float f) {
    union { float f; uint32 u; } v; v.f = f;
    uint32 r = v.u + 0x7fffu + ((v.u >> 16) & 1u);
    return (u16)(r >> 16);
}
static __device__ __forceinline__ float bf2f(u16 h) {
    union { uint32 u; float f; } v; v.u = ((uint32)h) << 16; return v.f;
}
static __device__ __forceinline__ uint32 pack2(float a, float b) {
    return (uint32)f2bf(a) | ((uint32)f2bf(b) << 16);
}
static __device__ __forceinline__ float blo(uint32 u){ union{uint32 u;float f;}v; v.u=u<<16; return v.f; }
static __device__ __forceinline__ float bhi(uint32 u){ union{uint32 u;float f;}v; v.u=u&0xffff0000u; return v.f; }

typedef __attribute__((address_space(1))) const void gas_void;
typedef __attribute__((address_space(3))) void las_void;
static __device__ __forceinline__ void glds16(const void* g, void* l) {
    __builtin_amdgcn_global_load_lds((gas_void*)g, (las_void*)l, 16, 0, 0);
}

// swizzle: XOR the 8-elem slot index with (row>>1)&3 -> 2 lanes/bank (free)
#define SWZ(c, row) ((c) ^ ((((row) >> 1) & 3) << 3))

#define VMCNT(N) asm volatile("s_waitcnt vmcnt(" #N ")" ::: "memory")
#define BARM() do { asm volatile("" ::: "memory"); __builtin_amdgcn_s_barrier(); asm volatile("" ::: "memory"); } while (0)

// tanh-form GELU: x - x/(exp(1.5957691x + 0.0713548x^3)+1), |err|<5e-4
static __device__ __forceinline__ float fast_gelu(float x) {
    float x2 = x * x;
    float w = x * fmaf(0.0713548162f, x2, 1.5957691216f);
    float e = __expf(w);
    float r = __builtin_amdgcn_rcpf(e + 1.0f);
    return fmaf(-x, r, x);
}

// ---------------- setup kernels ----------------

__global__ void wt_convert(const float* __restrict__ W, u16* __restrict__ WT, int K, int N) {
    long idx = (long)blockIdx.x * 256 + threadIdx.x;
    long tot = (long)K * N;
    if (idx >= tot) return;
    int n = (int)(idx / K), k = (int)(idx - (long)n * K);
    WT[(long)n * K + SWZ(k, n)] = f2bf(W[(long)k * N + n]);
}

__global__ void build_qkv_bias(const float* __restrict__ qb, const float* __restrict__ vb,
                               float* __restrict__ outb) {
    int c = blockIdx.x * 256 + threadIdx.x;
    if (c >= 1152) return;
    outb[c] = (c < 384) ? qb[c] : ((c < 768) ? 0.f : vb[c - 768]);
}

__global__ void cpb_tab(const float* __restrict__ table, const float* __restrict__ w1,
                        const float* __restrict__ b1, const float* __restrict__ w2,
                        float* __restrict__ tab) {
    __shared__ float hid[512];
    int e = blockIdx.x;
    float tx = table[e * 2 + 0], ty = table[e * 2 + 1];
    for (int u = threadIdx.x; u < 512; u += 256)
        hid[u] = fmaxf(tx * w1[u] + ty * w1[512 + u] + b1[u], 0.f);
    __syncthreads();
    if (threadIdx.x < 12) {
        float s = 0.f;
        for (int u = 0; u < 512; ++u) s += hid[u] * w2[u * 12 + threadIdx.x];
        tab[e * 12 + threadIdx.x] = s;
    }
}

__global__ void cpb_bias(const float* __restrict__ tab, const int* __restrict__ rpi,
                         float* __restrict__ bias16) {
    int idx = blockIdx.x * 256 + threadIdx.x;
    if (idx >= 12 * 144 * 144) return;
    int h = idx / 20736, ij = idx - h * 20736;
    float t = tab[rpi[ij] * 12 + h];
    bias16[idx] = 16.f / (1.f + __expf(-t));
}

__global__ void gather_xbf(const float* __restrict__ x, u16* __restrict__ xw) {
    int idx = blockIdx.x * 256 + threadIdx.x;
    if (idx >= 73728 * 48) return;
    int row = idx / 48, c = (idx - row * 48) * 8;
    int win = row / 144, n = row - win * 144;
    int b = win >> 4, wi = win & 15;
    int r = n / 12, cc = n - r * 12;
    int sh = ((wi >> 2) * 12 + r + 6) % 48;
    int sw = ((wi & 3) * 12 + cc + 6) % 48;
    long src = ((long)(b * 2304 + sh * 48 + sw)) * 384 + c;
    float4 f0 = *(const float4*)(x + src);
    float4 f1 = *(const float4*)(x + src + 4);
    uint4 o;
    o.x = pack2(f0.x, f0.y); o.y = pack2(f0.z, f0.w);
    o.z = pack2(f1.x, f1.y); o.w = pack2(f1.z, f1.w);
    *(uint4*)(xw + (long)row * 384 + SWZ(c, row)) = o;
}

// ---------------- GEMM ----------------

enum { EPI_PLAIN = 1, EPI_GELU = 2 };

template<int EPI, bool OSWZ, int NK>
__global__ __launch_bounds__(256, 2) void gemm_k(
    const u16* __restrict__ Ag, const u16* __restrict__ Bg,
    const float* __restrict__ bias, u16* __restrict__ outp,
    int N, int ntn)
{
    constexpr int K = NK * 32;
    extern __shared__ u16 lds[];          // As[3][8192] + Bs[3][4096] = 72KB
    u16* As = lds;
    u16* Bs = lds + 24576;

    const int tid = threadIdx.x, lane = tid & 63, wid = tid >> 6;
    const int qq = gridDim.x >> 3;
    const int wg = (blockIdx.x & 7) * qq + (blockIdx.x >> 3);
    const int mIdx = wg / ntn, nIdx = wg - mIdx * ntn;
    const int m0 = mIdx << 8, n0 = nIdx << 7;

    const int wrow = wid << 6;            // per-wave 64 rows x all 128 cols
    const int fr = lane & 15, gsel = lane >> 4;

    // staging: one glds16 = 64 lanes x 16B = 16 rows x 32 cols
    const int srow = (wid << 4) + (lane >> 2);
    const int scol = (lane & 3) << 3;
    const u16* aP[4];
    const u16* bP[2];
#pragma unroll
    for (int q = 0; q < 4; ++q) aP[q] = Ag + (long)(m0 + (q << 6) + srow) * K + scol;
#pragma unroll
    for (int q = 0; q < 2; ++q) bP[q] = Bg + (long)(n0 + (q << 6) + srow) * K + scol;

    auto stage = [&](int buf, int kt) {
#pragma unroll
        for (int q = 0; q < 4; ++q)
            glds16(aP[q] + (kt << 5), &As[buf * 8192 + ((q << 6) + (wid << 4)) * 32]);
#pragma unroll
        for (int q = 0; q < 2; ++q)
            glds16(bP[q] + (kt << 5), &Bs[buf * 4096 + ((q << 6) + (wid << 4)) * 32]);
    };

    int arow[4], acol[4], brow[8], bcol[8];
#pragma unroll
    for (int i = 0; i < 4; ++i) {
        arow[i] = wrow + i * 16 + fr;
        acol[i] = (gsel ^ ((arow[i] >> 1) & 3)) << 3;
    }
#pragma unroll
    for (int j = 0; j < 8; ++j) {
        brow[j] = j * 16 + fr;
        bcol[j] = (gsel ^ ((brow[j] >> 1) & 3)) << 3;
    }

    f32x4 acc[4][8];
    const f32x4 zero4 = {0.f, 0.f, 0.f, 0.f};
#pragma unroll
    for (int i = 0; i < 4; ++i)
#pragma unroll
        for (int j = 0; j < 8; ++j) acc[i][j] = zero4;

    auto compute = [&](int buf) {
        const u16* pa = As + buf * 8192;
        const u16* pb = Bs + buf * 4096;
        bf16x8 af[4], bg[8];
#pragma unroll
        for (int i = 0; i < 4; ++i) af[i] = *(const bf16x8*)&pa[arow[i] * 32 + acol[i]];
#pragma unroll
        for (int j = 0; j < 8; ++j) bg[j] = *(const bf16x8*)&pb[brow[j] * 32 + bcol[j]];
#pragma unroll
        for (int i = 0; i < 4; ++i)
#pragma unroll
            for (int j = 0; j < 8; ++j)
                acc[i][j] = __builtin_amdgcn_mfma_f32_16x16x32_bf16(af[i], bg[j], acc[i][j], 0, 0, 0);
    };

    // 3-deep ring, static buffer indices (period-3 groups; NK % 3 == 0)
    stage(0, 0);
    stage(1, 1);
#define GITER(KT, BC, BN_) \
    VMCNT(6); BARM(); stage(BN_, (KT) + 2); compute(BC);
    for (int g = 0; g < (NK - 1) / 3; ++g) {
        const int kb = g * 3;
        GITER(kb + 0, 0, 2);
        GITER(kb + 1, 1, 0);
        GITER(kb + 2, 2, 1);
    }
#undef GITER
    // tail: kt = NK-3, NK-2, NK-1  (bufs 0,1,2)
    VMCNT(6); BARM(); stage(2, NK - 1); compute(0);
    VMCNT(6); BARM(); compute(1);
    VMCNT(0); BARM(); compute(2);

    // ---------------- epilogue ----------------
    const int rbase = gsel << 2;
    float bv[8];
#pragma unroll
    for (int j = 0; j < 8; ++j) bv[j] = bias[n0 + j * 16 + fr];
#pragma unroll
    for (int i = 0; i < 4; ++i) {
#pragma unroll
        for (int r = 0; r < 4; ++r) {
            const int gm = m0 + wrow + i * 16 + rbase + r;
            u16* orow = outp + (long)gm * N;
            const int sx = OSWZ ? (((gm >> 1) & 3) << 3) : 0;
#pragma unroll
            for (int j = 0; j < 8; ++j) {
                const int gn = n0 + j * 16 + fr;
                float v = acc[i][j][r] + bv[j];
                if constexpr (EPI == EPI_GELU) v = fast_gelu(v);
                orow[gn ^ sx] = f2bf(v);
            }
        }
    }
}

// ---------------- attention: one (window, head) per block, 3 waves ----------------

__global__ __launch_bounds__(192) void attn_k(
    const u16* __restrict__ qkv,      // [73728][1152] bf16, plain rows
    const float* __restrict__ bias16, // [12][144][144]
    const float* __restrict__ mask,   // [16][144][144]
    const float* __restrict__ lsc,    // [12]
    u16* __restrict__ attn_o)         // [73728][384] bf16, swizzled cols
{
    __shared__ __align__(16) u16 KL[144][40];
    __shared__ __align__(16) u16 VT[32][168];
    __shared__ __align__(16) u16 PL[3][16][168];
    const int blk = blockIdx.x;
    const int win = blk / 12, head = blk - win * 12;
    const int tid = threadIdx.x, lane = tid & 63, wid = tid >> 6;
    const u16* Qp = qkv + (long)win * 144 * 1152 + head * 32;
    const u16* Kp = Qp + 384;
    const u16* Vp = Qp + 768;
    const float scale = __expf(fminf(lsc[head], 4.6051701859880914f));

    if (tid < 144) {
        const uint4* s = (const uint4*)(Kp + (long)tid * 1152);
        uint4 uu[4] = { s[0], s[1], s[2], s[3] };
        float f[32];
#pragma unroll
        for (int q = 0; q < 4; ++q) {
            f[q*8+0]=blo(uu[q].x); f[q*8+1]=bhi(uu[q].x);
            f[q*8+2]=blo(uu[q].y); f[q*8+3]=bhi(uu[q].y);
            f[q*8+4]=blo(uu[q].z); f[q*8+5]=bhi(uu[q].z);
            f[q*8+6]=blo(uu[q].w); f[q*8+7]=bhi(uu[q].w);
        }
        float ss = 0.f;
#pragma unroll
        for (int i = 0; i < 32; ++i) ss += f[i] * f[i];
        float inv = 1.f / fmaxf(sqrtf(ss), 1e-12f);
        uint32 pk[16];
#pragma unroll
        for (int i = 0; i < 16; ++i) pk[i] = pack2(f[2*i] * inv, f[2*i+1] * inv);
        uint4* d = (uint4*)&KL[tid][0];
        d[0] = make_uint4(pk[0], pk[1], pk[2], pk[3]);
        d[1] = make_uint4(pk[4], pk[5], pk[6], pk[7]);
        d[2] = make_uint4(pk[8], pk[9], pk[10], pk[11]);
        d[3] = make_uint4(pk[12], pk[13], pk[14], pk[15]);
        const uint4* sv = (const uint4*)(Vp + (long)tid * 1152);
        uint4 vv[4] = { sv[0], sv[1], sv[2], sv[3] };
        u16 vs[32];
#pragma unroll
        for (int q = 0; q < 4; ++q) {
            vs[q*8+0] = (u16)(vv[q].x & 0xffffu); vs[q*8+1] = (u16)(vv[q].x >> 16);
            vs[q*8+2] = (u16)(vv[q].y & 0xffffu); vs[q*8+3] = (u16)(vv[q].y >> 16);
            vs[q*8+4] = (u16)(vv[q].z & 0xffffu); vs[q*8+5] = (u16)(vv[q].z >> 16);
            vs[q*8+6] = (u16)(vv[q].w & 0xffffu); vs[q*8+7] = (u16)(vv[q].w >> 16);
        }
#pragma unroll
        for (int d2 = 0; d2 < 32; ++d2) VT[d2][tid] = vs[d2];
    }
    for (int idx = tid; idx < 512; idx += 192) VT[idx >> 4][144 + (idx & 15)] = 0;
    __syncthreads();

    const int fr = lane & 15, fk = (lane >> 4) << 3, rb = (lane >> 4) << 2;
    const int wim = win & 15;
    const f32x4 zero4 = {0.f, 0.f, 0.f, 0.f};

    for (int s = wid; s < 9; s += 3) {
        const uint4 qu = *(const uint4*)(Qp + (long)(s * 16 + fr) * 1152 + fk);
        float qf[8];
        qf[0]=blo(qu.x); qf[1]=bhi(qu.x); qf[2]=blo(qu.y); qf[3]=bhi(qu.y);
        qf[4]=blo(qu.z); qf[5]=bhi(qu.z); qf[6]=blo(qu.w); qf[7]=bhi(qu.w);
        float ss = 0.f;
#pragma unroll
        for (int i = 0; i < 8; ++i) ss += qf[i] * qf[i];
        ss += __shfl_xor(ss, 16);
        ss += __shfl_xor(ss, 32);
        float qinv = scale / fmaxf(sqrtf(ss), 1e-12f);
        union { uint32 u[4]; bf16x8 v; } cv;
#pragma unroll
        for (int i = 0; i < 4; ++i) cv.u[i] = pack2(qf[2*i] * qinv, qf[2*i+1] * qinv);
        bf16x8 aq = cv.v;

        f32x4 sacc[9];
#pragma unroll
        for (int jt = 0; jt < 9; ++jt) sacc[jt] = zero4;
#pragma unroll
        for (int jt = 0; jt < 9; ++jt) {
            bf16x8 bk = *(const bf16x8*)&KL[jt * 16 + fr][fk];
            sacc[jt] = __builtin_amdgcn_mfma_f32_16x16x32_bf16(aq, bk, sacc[jt], 0, 0, 0);
        }
        float mx[4] = {-1e30f, -1e30f, -1e30f, -1e30f};
#pragma unroll
        for (int jt = 0; jt < 9; ++jt) {
            int gj = jt * 16 + fr;
#pragma unroll
            for (int r = 0; r < 4; ++r) {
                int gi = s * 16 + rb + r;
                float v = sacc[jt][r] + bias16[(head * 144 + gi) * 144 + gj]
                                      + mask[(wim * 144 + gi) * 144 + gj];
                sacc[jt][r] = v;
                mx[r] = fmaxf(mx[r], v);
            }
        }
#pragma unroll
        for (int r = 0; r < 4; ++r) {
#pragma unroll
            for (int o = 1; o < 16; o <<= 1) mx[r] = fmaxf(mx[r], __shfl_xor(mx[r], o));
        }
        float sm[4] = {0.f, 0.f, 0.f, 0.f};
#pragma unroll
        for (int jt = 0; jt < 9; ++jt)
#pragma unroll
            for (int r = 0; r < 4; ++r) {
                float e = __expf(sacc[jt][r] - mx[r]);
                sacc[jt][r] = e;
                sm[r] += e;
            }
#pragma unroll
        for (int r = 0; r < 4; ++r) {
#pragma unroll
            for (int o = 1; o < 16; o <<= 1) sm[r] += __shfl_xor(sm[r], o);
            sm[r] = 1.f / sm[r];
        }
#pragma unroll
        for (int jt = 0; jt < 9; ++jt)
#pragma unroll
            for (int r = 0; r < 4; ++r)
                PL[wid][rb + r][jt * 16 + fr] = f2bf(sacc[jt][r]);
#pragma unroll
        for (int r = 0; r < 4; ++r) PL[wid][rb + r][144 + fr] = 0;

        f32x4 oa0 = zero4, oa1 = zero4;
#pragma unroll
        for (int kt = 0; kt < 5; ++kt) {
            bf16x8 ap  = *(const bf16x8*)&PL[wid][fr][kt * 32 + fk];
            bf16x8 bv0 = *(const bf16x8*)&VT[fr][kt * 32 + fk];
            bf16x8 bv1 = *(const bf16x8*)&VT[16 + fr][kt * 32 + fk];
            oa0 = __builtin_amdgcn_mfma_f32_16x16x32_bf16(ap, bv0, oa0, 0, 0, 0);
            oa1 = __builtin_amdgcn_mfma_f32_16x16x32_bf16(ap, bv1, oa1, 0, 0, 0);
        }
#pragma unroll
        for (int r = 0; r < 4; ++r) {
            long row = (long)win * 144 + s * 16 + rb + r;
            int c0 = head * 32 + fr, c1 = head * 32 + 16 + fr;
            attn_o[row * 384 + SWZ(c0, row)] = f2bf(oa0[r] * sm[r]);
            attn_o[row * 384 + SWZ(c1, row)] = f2bf(oa1[r] * sm[r]);
        }
    }
}

// ---------------- LayerNorm + residual (vectorized lanes) ----------------

__global__ __launch_bounds__(256) void ln1_k(
    const u16* __restrict__ pin, const float* __restrict__ x,
    const float* __restrict__ g, const float* __restrict__ bb,
    u16* __restrict__ y1b)
{
    const int token = blockIdx.x * 4 + (threadIdx.x >> 6);
    const int lane = threadIdx.x & 63;
    int b = token / 2304, hw = token - b * 2304;
    int h = hw / 48, w = hw - h * 48;
    int sh = h + 42; if (sh >= 48) sh -= 48;
    int sw = w + 42; if (sw >= 48) sw -= 48;
    int wh = sh / 12, r = sh - wh * 12;
    int ww = sw / 12, cc = sw - ww * 12;
    long srow = (long)(b * 16 + wh * 4 + ww) * 144 + r * 12 + cc;
    const u16* src = pin + srow * 384;
    const int c0 = lane * 4, c1 = 256 + lane * 2;
    uint2 p0 = *(const uint2*)(src + c0);
    uint32 p1 = *(const uint32*)(src + c1);
    float v[6] = { blo(p0.x), bhi(p0.x), blo(p0.y), bhi(p0.y), blo(p1), bhi(p1) };
    float s1 = 0.f, s2 = 0.f;
#pragma unroll
    for (int i = 0; i < 6; ++i) { s1 += v[i]; s2 += v[i] * v[i]; }
#pragma unroll
    for (int o = 1; o < 64; o <<= 1) { s1 += __shfl_xor(s1, o); s2 += __shfl_xor(s2, o); }
    float mean = s1 * (1.f / 384.f);
    float var = s2 * (1.f / 384.f) - mean * mean;
    float rs = rsqrtf(var + 1e-5f);
    const float* xx = x + (long)token * 384;
    float4 r0 = *(const float4*)(xx + c0);
    float2 r1 = *(const float2*)(xx + c1);
    float4 g0 = *(const float4*)(g + c0);
    float2 g1 = *(const float2*)(g + c1);
    float4 b0 = *(const float4*)(bb + c0);
    float2 b1 = *(const float2*)(bb + c1);
    float o0 = r0.x + (v[0] - mean) * rs * g0.x + b0.x;
    float o1 = r0.y + (v[1] - mean) * rs * g0.y + b0.y;
    float o2 = r0.z + (v[2] - mean) * rs * g0.z + b0.z;
    float o3 = r0.w + (v[3] - mean) * rs * g0.w + b0.w;
    float o4 = r1.x + (v[4] - mean) * rs * g1.x + b1.x;
    float o5 = r1.y + (v[5] - mean) * rs * g1.y + b1.y;
    u16* oo = y1b + (long)token * 384;
    const int sx = ((token >> 1) & 3) << 3;
    uint2 w0; w0.x = pack2(o0, o1); w0.y = pack2(o2, o3);
    *(uint2*)(oo + (c0 ^ sx)) = w0;
    *(uint32*)(oo + (c1 ^ sx)) = pack2(o4, o5);
}

__global__ __launch_bounds__(256) void ln2_k(
    const u16* __restrict__ t2, const u16* __restrict__ y1b,
    const float* __restrict__ g, const float* __restrict__ bb,
    float* __restrict__ outp)
{
    const int token = blockIdx.x * 4 + (threadIdx.x >> 6);
    const int lane = threadIdx.x & 63;
    const int c0 = lane * 4, c1 = 256 + lane * 2;
    const u16* src = t2 + (long)token * 384;
    uint2 p0 = *(const uint2*)(src + c0);
    uint32 p1 = *(const uint32*)(src + c1);
    float v[6] = { blo(p0.x), bhi(p0.x), blo(p0.y), bhi(p0.y), blo(p1), bhi(p1) };
    float s1 = 0.f, s2 = 0.f;
#pragma unroll
    for (int i = 0; i < 6; ++i) { s1 += v[i]; s2 += v[i] * v[i]; }
#pragma unroll
    for (int o = 1; o < 64; o <<= 1) { s1 += __shfl_xor(s1, o); s2 += __shfl_xor(s2, o); }
    float mean = s1 * (1.f / 384.f);
    float var = s2 * (1.f / 384.f) - mean * mean;
    float rs = rsqrtf(var + 1e-5f);
    const u16* rr = y1b + (long)token * 384;
    const int sx = ((token >> 1) & 3) << 3;
    uint2 q0 = *(const uint2*)(rr + (c0 ^ sx));
    uint32 q1 = *(const uint32*)(rr + (c1 ^ sx));
    float4 g0 = *(const float4*)(g + c0);
    float2 g1 = *(const float2*)(g + c1);
    float4 b0 = *(const float4*)(bb + c0);
    float2 b1 = *(const float2*)(bb + c1);
    float* oo = outp + (long)token * 384;
    float4 w0;
    w0.x = blo(q0.x) + (v[0] - mean) * rs * g0.x + b0.x;
    w0.y = bhi(q0.x) + (v[1] - mean) * rs * g0.y + b0.y;
    w0.z = blo(q0.y) + (v[2] - mean) * rs * g0.z + b0.z;
    w0.w = bhi(q0.y) + (v[3] - mean) * rs * g0.w + b0.w;
    float2 w1;
    w1.x = blo(q1) + (v[4] - mean) * rs * g1.x + b1.x;
    w1.y = bhi(q1) + (v[5] - mean) * rs * g1.y + b1.y;
    *(float4*)(oo + c0) = w0;
    *(float2*)(oo + c1) = w1;
}

// ---------------- launch ----------------

extern "C" void kernel_launch(void* const* d_in, const int* in_sizes, int n_in,
                              void* d_out, int out_size, void* d_ws, size_t ws_size,
                              hipStream_t stream) {
    (void)in_sizes; (void)n_in; (void)out_size; (void)ws_size;
    const float* x      = (const float*)d_in[0];
    const float* table  = (const float*)d_in[1];
    const int*   rpi    = (const int*)d_in[2];
    const float* mask   = (const float*)d_in[3];
    const float* qkv_w  = (const float*)d_in[4];
    const float* q_bias = (const float*)d_in[5];
    const float* v_bias = (const float*)d_in[6];
    const float* lsc    = (const float*)d_in[7];
    const float* cpb_w1 = (const float*)d_in[8];
    const float* cpb_b1 = (const float*)d_in[9];
    const float* cpb_w2 = (const float*)d_in[10];
    const float* proj_w = (const float*)d_in[11];
    const float* proj_b = (const float*)d_in[12];
    const float* n1g    = (const float*)d_in[13];
    const float* n1b    = (const float*)d_in[14];
    const float* n2g    = (const float*)d_in[15];
    const float* n2b    = (const float*)d_in[16];
    const float* fc1_w  = (const float*)d_in[17];
    const float* fc1_b  = (const float*)d_in[18];
    const float* fc2_w  = (const float*)d_in[19];
    const float* fc2_b  = (const float*)d_in[20];
    float* outp = (float*)d_out;

    char* ws = (char*)d_ws;
    const size_t offA    = 0;                       // qkvb(170MB) -> proj_o -> hbuf(226MB)
    const size_t offB    = 226492416;               // attn_o -> t2 (56.6MB)
    const size_t offC    = offB + 56623104;         // xw -> y1b (56.6MB)
    const size_t offBias = offC + 56623104;
    const size_t offTab  = offBias + 995328;
    const size_t offQW   = offTab + 25600;
    const size_t offPW   = offQW + 884736;
    const size_t offF1   = offPW + 294912;
    const size_t offF2   = offF1 + 1179648;
    const size_t offQB   = offF2 + 1179648;

    u16*   qkvb    = (u16*)(ws + offA);
    u16*   proj_o  = (u16*)(ws + offA);
    u16*   hbuf    = (u16*)(ws + offA);
    u16*   attn_o  = (u16*)(ws + offB);
    u16*   t2      = (u16*)(ws + offB);
    u16*   xw      = (u16*)(ws + offC);
    u16*   y1b     = (u16*)(ws + offC);
    float* bias16  = (float*)(ws + offBias);
    float* tab     = (float*)(ws + offTab);
    u16*   qkv_wT  = (u16*)(ws + offQW);
    u16*   proj_wT = (u16*)(ws + offPW);
    u16*   fc1_wT  = (u16*)(ws + offF1);
    u16*   fc2_wT  = (u16*)(ws + offF2);
    float* qkvbias = (float*)(ws + offQB);

    hipFuncSetAttribute((const void*)&gemm_k<EPI_PLAIN, false, 12>,
                        hipFuncAttributeMaxDynamicSharedMemorySize, 73728);
    hipFuncSetAttribute((const void*)&gemm_k<EPI_GELU, true, 12>,
                        hipFuncAttributeMaxDynamicSharedMemorySize, 73728);
    hipFuncSetAttribute((const void*)&gemm_k<EPI_PLAIN, false, 48>,
                        hipFuncAttributeMaxDynamicSharedMemorySize, 73728);

    wt_convert<<<(384 * 1152 + 255) / 256, 256, 0, stream>>>(qkv_w, qkv_wT, 384, 1152);
    wt_convert<<<(384 * 384 + 255) / 256, 256, 0, stream>>>(proj_w, proj_wT, 384, 384);
    wt_convert<<<(384 * 1536 + 255) / 256, 256, 0, stream>>>(fc1_w, fc1_wT, 384, 1536);
    wt_convert<<<(1536 * 384 + 255) / 256, 256, 0, stream>>>(fc2_w, fc2_wT, 1536, 384);
    build_qkv_bias<<<5, 256, 0, stream>>>(q_bias, v_bias, qkvbias);
    cpb_tab<<<529, 256, 0, stream>>>(table, cpb_w1, cpb_b1, cpb_w2, tab);
    cpb_bias<<<(12 * 144 * 144 + 255) / 256, 256, 0, stream>>>(tab, rpi, bias16);
    gather_xbf<<<(73728 * 48 + 255) / 256, 256, 0, stream>>>(x, xw);

    // qkv: plain [73728][1152]
    gemm_k<EPI_PLAIN, false, 12><<<288 * 9, 256, 73728, stream>>>(xw, qkv_wT, qkvbias, qkvb, 1152, 9);

    attn_k<<<6144, 192, 0, stream>>>(qkvb, bias16, mask, lsc, attn_o);

    gemm_k<EPI_PLAIN, false, 12><<<288 * 3, 256, 73728, stream>>>(attn_o, proj_wT, proj_b, proj_o, 384, 3);

    ln1_k<<<18432, 256, 0, stream>>>(proj_o, x, n1g, n1b, y1b);

    gemm_k<EPI_GELU, true, 12><<<288 * 12, 256, 73728, stream>>>(y1b, fc1_wT, fc1_b, hbuf, 1536, 12);

    gemm_k<EPI_PLAIN, false, 48><<<288 * 3, 256, 73728, stream>>>(hbuf, fc2_wT, fc2_b, t2, 384, 3);

    ln2_k<<<18432, 256, 0, stream>>>(t2, y1b, n2g, n2b, outp);
}

// Round 9
// 702.644 us; speedup vs baseline: 2.8260x; 1.0270x over previous
//
#include <hip/hip_runtime.h>

// SwinV2 block, MI355X. GEMMs: bf16 MFMA 16x16x32, fp32 accum, BM=256 x
// BN=128, 4 waves x (64x128), BK=32, 3-deep ring LDS (72KB dynamic) with
// STATIC buffer indices + counted vmcnt(6) + raw s_barrier, launch_bounds
// (256,2) (no spill). Producer-side XOR swizzle -> 0 bank conflicts.
// Attn: combined (bias+mask)*log2e fp32 table, exp2-domain softmax,
// native v_cvt bf16 conversions.

typedef unsigned int uint32;
typedef unsigned short u16;
typedef __attribute__((ext_vector_type(4))) float f32x4;
typedef __attribute__((ext_vector_type(8))) __bf16 bf16x8;

#define LOG2E 1.4426950408889634f

static __device__ __forceinline__ u16 f2bf(float f) {
    union { __bf16 b; u16 u; } v; v.b = (__bf16)f; return v.u;   // v_cvt (RNE)
}
static __device__ __forceinline__ uint32 pack2(float a, float b) {
    union { __bf16 h[2]; uint32 u; } v;
    v.h[0] = (__bf16)a; v.h[1] = (__bf16)b; return v.u;          // v_cvt_pk
}
static __device__ __forceinline__ float blo(uint32 u){ union{uint32 u;float f;}v; v.u=u<<16; return v.f; }
static __device__ __forceinline__ float bhi(uint32 u){ union{uint32 u;float f;}v; v.u=u&0xffff0000u; return v.f; }

typedef __attribute__((address_space(1))) const void gas_void;
typedef __attribute__((address_space(3))) void las_void;
static __device__ __forceinline__ void glds16(const void* g, void* l) {
    __builtin_amdgcn_global_load_lds((gas_void*)g, (las_void*)l, 16, 0, 0);
}

// swizzle: XOR the 8-elem slot index with (row>>1)&3 -> 2 lanes/bank (free)
#define SWZ(c, row) ((c) ^ ((((row) >> 1) & 3) << 3))

#define VMCNT(N) asm volatile("s_waitcnt vmcnt(" #N ")" ::: "memory")
#define BARM() do { asm volatile("" ::: "memory"); __builtin_amdgcn_s_barrier(); asm volatile("" ::: "memory"); } while (0)

// tanh-form GELU, exp2-folded: |err|<5e-4
static __device__ __forceinline__ float fast_gelu(float x) {
    float x2 = x * x;
    float w = x * fmaf(0.10294842f, x2, 2.30226005f);  // (a,b)*log2e
    float e = exp2f(w);
    float r = __builtin_amdgcn_rcpf(e + 1.0f);
    return fmaf(-x, r, x);
}

// ---------------- setup kernels ----------------

__global__ void wt_convert(const float* __restrict__ W, u16* __restrict__ WT, int K, int N) {
    long idx = (long)blockIdx.x * 256 + threadIdx.x;
    long tot = (long)K * N;
    if (idx >= tot) return;
    int n = (int)(idx / K), k = (int)(idx - (long)n * K);
    WT[(long)n * K + SWZ(k, n)] = f2bf(W[(long)k * N + n]);
}

__global__ void build_qkv_bias(const float* __restrict__ qb, const float* __restrict__ vb,
                               float* __restrict__ outb) {
    int c = blockIdx.x * 256 + threadIdx.x;
    if (c >= 1152) return;
    outb[c] = (c < 384) ? qb[c] : ((c < 768) ? 0.f : vb[c - 768]);
}

__global__ void cpb_tab(const float* __restrict__ table, const float* __restrict__ w1,
                        const float* __restrict__ b1, const float* __restrict__ w2,
                        float* __restrict__ tab) {
    __shared__ float hid[512];
    int e = blockIdx.x;
    float tx = table[e * 2 + 0], ty = table[e * 2 + 1];
    for (int u = threadIdx.x; u < 512; u += 256)
        hid[u] = fmaxf(tx * w1[u] + ty * w1[512 + u] + b1[u], 0.f);
    __syncthreads();
    if (threadIdx.x < 12) {
        float s = 0.f;
        for (int u = 0; u < 512; ++u) s += hid[u] * w2[u * 12 + threadIdx.x];
        tab[e * 12 + threadIdx.x] = s;
    }
}

// bm[h][wim][i][j] = (16*sigmoid(cpb) + mask) * log2e   (fp32, 16MB)
__global__ void build_bm(const float* __restrict__ tab, const int* __restrict__ rpi,
                         const float* __restrict__ mask, float* __restrict__ bm) {
    int idx = blockIdx.x * 256 + threadIdx.x;
    if (idx >= 12 * 16 * 20736) return;
    int h = idx / 331776, rem = idx - h * 331776;
    int wim = rem / 20736, ij = rem - wim * 20736;
    float t = tab[rpi[ij] * 12 + h];
    float bias = 16.f / (1.f + __expf(-t));
    bm[idx] = (bias + mask[wim * 20736 + ij]) * LOG2E;
}

__global__ void gather_xbf(const float* __restrict__ x, u16* __restrict__ xw) {
    int idx = blockIdx.x * 256 + threadIdx.x;
    if (idx >= 73728 * 48) return;
    int row = idx / 48, c = (idx - row * 48) * 8;
    int win = row / 144, n = row - win * 144;
    int b = win >> 4, wi = win & 15;
    int r = n / 12, cc = n - r * 12;
    int sh = ((wi >> 2) * 12 + r + 6) % 48;
    int sw = ((wi & 3) * 12 + cc + 6) % 48;
    long src = ((long)(b * 2304 + sh * 48 + sw)) * 384 + c;
    float4 f0 = *(const float4*)(x + src);
    float4 f1 = *(const float4*)(x + src + 4);
    uint4 o;
    o.x = pack2(f0.x, f0.y); o.y = pack2(f0.z, f0.w);
    o.z = pack2(f1.x, f1.y); o.w = pack2(f1.z, f1.w);
    *(uint4*)(xw + (long)row * 384 + SWZ(c, row)) = o;
}

// ---------------- GEMM ----------------

enum { EPI_PLAIN = 1, EPI_GELU = 2 };

template<int EPI, bool OSWZ, int NK>
__global__ __launch_bounds__(256, 2) void gemm_k(
    const u16* __restrict__ Ag, const u16* __restrict__ Bg,
    const float* __restrict__ bias, u16* __restrict__ outp,
    int N, int ntn)
{
    constexpr int K = NK * 32;
    extern __shared__ u16 lds[];          // As[3][8192] + Bs[3][4096] = 72KB
    u16* As = lds;
    u16* Bs = lds + 24576;

    const int tid = threadIdx.x, lane = tid & 63, wid = tid >> 6;
    const int qq = gridDim.x >> 3;
    const int wg = (blockIdx.x & 7) * qq + (blockIdx.x >> 3);
    const int mIdx = wg / ntn, nIdx = wg - mIdx * ntn;
    const int m0 = mIdx << 8, n0 = nIdx << 7;

    const int wrow = wid << 6;            // per-wave 64 rows x all 128 cols
    const int fr = lane & 15, gsel = lane >> 4;

    const int srow = (wid << 4) + (lane >> 2);
    const int scol = (lane & 3) << 3;
    const u16* aP[4];
    const u16* bP[2];
#pragma unroll
    for (int q = 0; q < 4; ++q) aP[q] = Ag + (long)(m0 + (q << 6) + srow) * K + scol;
#pragma unroll
    for (int q = 0; q < 2; ++q) bP[q] = Bg + (long)(n0 + (q << 6) + srow) * K + scol;

    auto stage = [&](int buf, int kt) {
#pragma unroll
        for (int q = 0; q < 4; ++q)
            glds16(aP[q] + (kt << 5), &As[buf * 8192 + ((q << 6) + (wid << 4)) * 32]);
#pragma unroll
        for (int q = 0; q < 2; ++q)
            glds16(bP[q] + (kt << 5), &Bs[buf * 4096 + ((q << 6) + (wid << 4)) * 32]);
    };

    int arow[4], acol[4], brow[8], bcol[8];
#pragma unroll
    for (int i = 0; i < 4; ++i) {
        arow[i] = wrow + i * 16 + fr;
        acol[i] = (gsel ^ ((arow[i] >> 1) & 3)) << 3;
    }
#pragma unroll
    for (int j = 0; j < 8; ++j) {
        brow[j] = j * 16 + fr;
        bcol[j] = (gsel ^ ((brow[j] >> 1) & 3)) << 3;
    }

    f32x4 acc[4][8];
    const f32x4 zero4 = {0.f, 0.f, 0.f, 0.f};
#pragma unroll
    for (int i = 0; i < 4; ++i)
#pragma unroll
        for (int j = 0; j < 8; ++j) acc[i][j] = zero4;

    auto compute = [&](int buf) {
        const u16* pa = As + buf * 8192;
        const u16* pb = Bs + buf * 4096;
        bf16x8 af[4], bg[8];
#pragma unroll
        for (int i = 0; i < 4; ++i) af[i] = *(const bf16x8*)&pa[arow[i] * 32 + acol[i]];
#pragma unroll
        for (int j = 0; j < 8; ++j) bg[j] = *(const bf16x8*)&pb[brow[j] * 32 + bcol[j]];
#pragma unroll
        for (int i = 0; i < 4; ++i)
#pragma unroll
            for (int j = 0; j < 8; ++j)
                acc[i][j] = __builtin_amdgcn_mfma_f32_16x16x32_bf16(af[i], bg[j], acc[i][j], 0, 0, 0);
    };

    // 3-deep ring, static buffer indices (NK % 3 == 0)
    stage(0, 0);
    stage(1, 1);
#define GITER(KT, BC, BN_) \
    VMCNT(6); BARM(); stage(BN_, (KT) + 2); compute(BC);
    for (int g = 0; g < (NK - 1) / 3; ++g) {
        const int kb = g * 3;
        GITER(kb + 0, 0, 2);
        GITER(kb + 1, 1, 0);
        GITER(kb + 2, 2, 1);
    }
#undef GITER
    VMCNT(6); BARM(); stage(2, NK - 1); compute(0);
    VMCNT(6); BARM(); compute(1);
    VMCNT(0); BARM(); compute(2);

    // ---------------- epilogue ----------------
    const int rbase = gsel << 2;
    float bv[8];
#pragma unroll
    for (int j = 0; j < 8; ++j) bv[j] = bias[n0 + j * 16 + fr];
#pragma unroll
    for (int i = 0; i < 4; ++i) {
#pragma unroll
        for (int r = 0; r < 4; ++r) {
            const int gm = m0 + wrow + i * 16 + rbase + r;
            u16* orow = outp + (long)gm * N;
            const int sx = OSWZ ? (((gm >> 1) & 3) << 3) : 0;
#pragma unroll
            for (int j = 0; j < 8; ++j) {
                const int gn = n0 + j * 16 + fr;
                float v = acc[i][j][r] + bv[j];
                if constexpr (EPI == EPI_GELU) v = fast_gelu(v);
                orow[gn ^ sx] = f2bf(v);
            }
        }
    }
}

// ---------------- attention: one (window, head) per block, 3 waves ----------------

__global__ __launch_bounds__(192) void attn_k(
    const u16* __restrict__ qkv,      // [73728][1152] bf16, plain rows
    const float* __restrict__ bm,     // [12][16][144][144] (bias+mask)*log2e
    const float* __restrict__ lsc,    // [12]
    u16* __restrict__ attn_o)         // [73728][384] bf16, swizzled cols
{
    __shared__ __align__(16) u16 KL[144][40];
    __shared__ __align__(16) u16 VT[32][168];
    __shared__ __align__(16) u16 PL[3][16][168];
    const int blk = blockIdx.x;
    const int win = blk / 12, head = blk - win * 12;
    const int tid = threadIdx.x, lane = tid & 63, wid = tid >> 6;
    const u16* Qp = qkv + (long)win * 144 * 1152 + head * 32;
    const u16* Kp = Qp + 384;
    const u16* Vp = Qp + 768;
    // scale * log2e (softmax computed in exp2 domain)
    const float scale = __expf(fminf(lsc[head], 4.6051701859880914f)) * LOG2E;
    const float* bmp = bm + ((long)head * 16 + (win & 15)) * 20736;

    if (tid < 144) {
        const uint4* s = (const uint4*)(Kp + (long)tid * 1152);
        uint4 uu[4] = { s[0], s[1], s[2], s[3] };
        float f[32];
#pragma unroll
        for (int q = 0; q < 4; ++q) {
            f[q*8+0]=blo(uu[q].x); f[q*8+1]=bhi(uu[q].x);
            f[q*8+2]=blo(uu[q].y); f[q*8+3]=bhi(uu[q].y);
            f[q*8+4]=blo(uu[q].z); f[q*8+5]=bhi(uu[q].z);
            f[q*8+6]=blo(uu[q].w); f[q*8+7]=bhi(uu[q].w);
        }
        float ss = 0.f;
#pragma unroll
        for (int i = 0; i < 32; ++i) ss += f[i] * f[i];
        float inv = 1.f / fmaxf(sqrtf(ss), 1e-12f);
        uint32 pk[16];
#pragma unroll
        for (int i = 0; i < 16; ++i) pk[i] = pack2(f[2*i] * inv, f[2*i+1] * inv);
        uint4* d = (uint4*)&KL[tid][0];
        d[0] = make_uint4(pk[0], pk[1], pk[2], pk[3]);
        d[1] = make_uint4(pk[4], pk[5], pk[6], pk[7]);
        d[2] = make_uint4(pk[8], pk[9], pk[10], pk[11]);
        d[3] = make_uint4(pk[12], pk[13], pk[14], pk[15]);
        const uint4* sv = (const uint4*)(Vp + (long)tid * 1152);
        uint4 vv[4] = { sv[0], sv[1], sv[2], sv[3] };
        u16 vs[32];
#pragma unroll
        for (int q = 0; q < 4; ++q) {
            vs[q*8+0] = (u16)(vv[q].x & 0xffffu); vs[q*8+1] = (u16)(vv[q].x >> 16);
            vs[q*8+2] = (u16)(vv[q].y & 0xffffu); vs[q*8+3] = (u16)(vv[q].y >> 16);
            vs[q*8+4] = (u16)(vv[q].z & 0xffffu); vs[q*8+5] = (u16)(vv[q].z >> 16);
            vs[q*8+6] = (u16)(vv[q].w & 0xffffu); vs[q*8+7] = (u16)(vv[q].w >> 16);
        }
#pragma unroll
        for (int d2 = 0; d2 < 32; ++d2) VT[d2][tid] = vs[d2];
    }
    for (int idx = tid; idx < 512; idx += 192) VT[idx >> 4][144 + (idx & 15)] = 0;
    __syncthreads();

    const int fr = lane & 15, fk = (lane >> 4) << 3, rb = (lane >> 4) << 2;
    const f32x4 zero4 = {0.f, 0.f, 0.f, 0.f};

    for (int s = wid; s < 9; s += 3) {
        const uint4 qu = *(const uint4*)(Qp + (long)(s * 16 + fr) * 1152 + fk);
        float qf[8];
        qf[0]=blo(qu.x); qf[1]=bhi(qu.x); qf[2]=blo(qu.y); qf[3]=bhi(qu.y);
        qf[4]=blo(qu.z); qf[5]=bhi(qu.z); qf[6]=blo(qu.w); qf[7]=bhi(qu.w);
        float ss = 0.f;
#pragma unroll
        for (int i = 0; i < 8; ++i) ss += qf[i] * qf[i];
        ss += __shfl_xor(ss, 16);
        ss += __shfl_xor(ss, 32);
        float qinv = scale / fmaxf(sqrtf(ss), 1e-12f);
        union { uint32 u[4]; bf16x8 v; } cv;
#pragma unroll
        for (int i = 0; i < 4; ++i) cv.u[i] = pack2(qf[2*i] * qinv, qf[2*i+1] * qinv);
        bf16x8 aq = cv.v;

        f32x4 sacc[9];
#pragma unroll
        for (int jt = 0; jt < 9; ++jt) sacc[jt] = zero4;
#pragma unroll
        for (int jt = 0; jt < 9; ++jt) {
            bf16x8 bk = *(const bf16x8*)&KL[jt * 16 + fr][fk];
            sacc[jt] = __builtin_amdgcn_mfma_f32_16x16x32_bf16(aq, bk, sacc[jt], 0, 0, 0);
        }
        float mx[4] = {-1e30f, -1e30f, -1e30f, -1e30f};
#pragma unroll
        for (int jt = 0; jt < 9; ++jt) {
            int gj = jt * 16 + fr;
#pragma unroll
            for (int r = 0; r < 4; ++r) {
                int gi = s * 16 + rb + r;
                float v = sacc[jt][r] + bmp[gi * 144 + gj];
                sacc[jt][r] = v;
                mx[r] = fmaxf(mx[r], v);
            }
        }
#pragma unroll
        for (int r = 0; r < 4; ++r) {
#pragma unroll
            for (int o = 1; o < 16; o <<= 1) mx[r] = fmaxf(mx[r], __shfl_xor(mx[r], o));
        }
        float sm[4] = {0.f, 0.f, 0.f, 0.f};
#pragma unroll
        for (int jt = 0; jt < 9; ++jt)
#pragma unroll
            for (int r = 0; r < 4; ++r) {
                float e = exp2f(sacc[jt][r] - mx[r]);
                sacc[jt][r] = e;
                sm[r] += e;
            }
#pragma unroll
        for (int r = 0; r < 4; ++r) {
#pragma unroll
            for (int o = 1; o < 16; o <<= 1) sm[r] += __shfl_xor(sm[r], o);
            sm[r] = 1.f / sm[r];
        }
#pragma unroll
        for (int jt = 0; jt < 9; ++jt)
#pragma unroll
            for (int r = 0; r < 4; ++r)
                PL[wid][rb + r][jt * 16 + fr] = f2bf(sacc[jt][r]);
#pragma unroll
        for (int r = 0; r < 4; ++r) PL[wid][rb + r][144 + fr] = 0;

        f32x4 oa0 = zero4, oa1 = zero4;
#pragma unroll
        for (int kt = 0; kt < 5; ++kt) {
            bf16x8 ap  = *(const bf16x8*)&PL[wid][fr][kt * 32 + fk];
            bf16x8 bv0 = *(const bf16x8*)&VT[fr][kt * 32 + fk];
            bf16x8 bv1 = *(const bf16x8*)&VT[16 + fr][kt * 32 + fk];
            oa0 = __builtin_amdgcn_mfma_f32_16x16x32_bf16(ap, bv0, oa0, 0, 0, 0);
            oa1 = __builtin_amdgcn_mfma_f32_16x16x32_bf16(ap, bv1, oa1, 0, 0, 0);
        }
#pragma unroll
        for (int r = 0; r < 4; ++r) {
            long row = (long)win * 144 + s * 16 + rb + r;
            int c0 = head * 32 + fr, c1 = head * 32 + 16 + fr;
            attn_o[row * 384 + SWZ(c0, row)] = f2bf(oa0[r] * sm[r]);
            attn_o[row * 384 + SWZ(c1, row)] = f2bf(oa1[r] * sm[r]);
        }
    }
}

// ---------------- LayerNorm + residual (vectorized lanes) ----------------

__global__ __launch_bounds__(256) void ln1_k(
    const u16* __restrict__ pin, const float* __restrict__ x,
    const float* __restrict__ g, const float* __restrict__ bb,
    u16* __restrict__ y1b)
{
    const int token = blockIdx.x * 4 + (threadIdx.x >> 6);
    const int lane = threadIdx.x & 63;
    int b = token / 2304, hw = token - b * 2304;
    int h = hw / 48, w = hw - h * 48;
    int sh = h + 42; if (sh >= 48) sh -= 48;
    int sw = w + 42; if (sw >= 48) sw -= 48;
    int wh = sh / 12, r = sh - wh * 12;
    int ww = sw / 12, cc = sw - ww * 12;
    long srow = (long)(b * 16 + wh * 4 + ww) * 144 + r * 12 + cc;
    const u16* src = pin + srow * 384;
    const int c0 = lane * 4, c1 = 256 + lane * 2;
    uint2 p0 = *(const uint2*)(src + c0);
    uint32 p1 = *(const uint32*)(src + c1);
    float v[6] = { blo(p0.x), bhi(p0.x), blo(p0.y), bhi(p0.y), blo(p1), bhi(p1) };
    float s1 = 0.f, s2 = 0.f;
#pragma unroll
    for (int i = 0; i < 6; ++i) { s1 += v[i]; s2 += v[i] * v[i]; }
#pragma unroll
    for (int o = 1; o < 64; o <<= 1) { s1 += __shfl_xor(s1, o); s2 += __shfl_xor(s2, o); }
    float mean = s1 * (1.f / 384.f);
    float var = s2 * (1.f / 384.f) - mean * mean;
    float rs = rsqrtf(var + 1e-5f);
    const float* xx = x + (long)token * 384;
    float4 r0 = *(const float4*)(xx + c0);
    float2 r1 = *(const float2*)(xx + c1);
    float4 g0 = *(const float4*)(g + c0);
    float2 g1 = *(const float2*)(g + c1);
    float4 b0 = *(const float4*)(bb + c0);
    float2 b1 = *(const float2*)(bb + c1);
    float o0 = r0.x + (v[0] - mean) * rs * g0.x + b0.x;
    float o1 = r0.y + (v[1] - mean) * rs * g0.y + b0.y;
    float o2 = r0.z + (v[2] - mean) * rs * g0.z + b0.z;
    float o3 = r0.w + (v[3] - mean) * rs * g0.w + b0.w;
    float o4 = r1.x + (v[4] - mean) * rs * g1.x + b1.x;
    float o5 = r1.y + (v[5] - mean) * rs * g1.y + b1.y;
    u16* oo = y1b + (long)token * 384;
    const int sx = ((token >> 1) & 3) << 3;
    uint2 w0; w0.x = pack2(o0, o1); w0.y = pack2(o2, o3);
    *(uint2*)(oo + (c0 ^ sx)) = w0;
    *(uint32*)(oo + (c1 ^ sx)) = pack2(o4, o5);
}

__global__ __launch_bounds__(256) void ln2_k(
    const u16* __restrict__ t2, const u16* __restrict__ y1b,
    const float* __restrict__ g, const float* __restrict__ bb,
    float* __restrict__ outp)
{
    const int token = blockIdx.x * 4 + (threadIdx.x >> 6);
    const int lane = threadIdx.x & 63;
    const int c0 = lane * 4, c1 = 256 + lane * 2;
    const u16* src = t2 + (long)token * 384;
    uint2 p0 = *(const uint2*)(src + c0);
    uint32 p1 = *(const uint32*)(src + c1);
    float v[6] = { blo(p0.x), bhi(p0.x), blo(p0.y), bhi(p0.y), blo(p1), bhi(p1) };
    float s1 = 0.f, s2 = 0.f;
#pragma unroll
    for (int i = 0; i < 6; ++i) { s1 += v[i]; s2 += v[i] * v[i]; }
#pragma unroll
    for (int o = 1; o < 64; o <<= 1) { s1 += __shfl_xor(s1, o); s2 += __shfl_xor(s2, o); }
    float mean = s1 * (1.f / 384.f);
    float var = s2 * (1.f / 384.f) - mean * mean;
    float rs = rsqrtf(var + 1e-5f);
    const u16* rr = y1b + (long)token * 384;
    const int sx = ((token >> 1) & 3) << 3;
    uint2 q0 = *(const uint2*)(rr + (c0 ^ sx));
    uint32 q1 = *(const uint32*)(rr + (c1 ^ sx));
    float4 g0 = *(const float4*)(g + c0);
    float2 g1 = *(const float2*)(g + c1);
    float4 b0 = *(const float4*)(bb + c0);
    float2 b1 = *(const float2*)(bb + c1);
    float* oo = outp + (long)token * 384;
    float4 w0;
    w0.x = blo(q0.x) + (v[0] - mean) * rs * g0.x + b0.x;
    w0.y = bhi(q0.x) + (v[1] - mean) * rs * g0.y + b0.y;
    w0.z = blo(q0.y) + (v[2] - mean) * rs * g0.z + b0.z;
    w0.w = bhi(q0.y) + (v[3] - mean) * rs * g0.w + b0.w;
    float2 w1;
    w1.x = blo(q1) + (v[4] - mean) * rs * g1.x + b1.x;
    w1.y = bhi(q1) + (v[5] - mean) * rs * g1.y + b1.y;
    *(float4*)(oo + c0) = w0;
    *(float2*)(oo + c1) = w1;
}

// ---------------- launch ----------------

extern "C" void kernel_launch(void* const* d_in, const int* in_sizes, int n_in,
                              void* d_out, int out_size, void* d_ws, size_t ws_size,
                              hipStream_t stream) {
    (void)in_sizes; (void)n_in; (void)out_size; (void)ws_size;
    const float* x      = (const float*)d_in[0];
    const float* table  = (const float*)d_in[1];
    const int*   rpi    = (const int*)d_in[2];
    const float* mask   = (const float*)d_in[3];
    const float* qkv_w  = (const float*)d_in[4];
    const float* q_bias = (const float*)d_in[5];
    const float* v_bias = (const float*)d_in[6];
    const float* lsc    = (const float*)d_in[7];
    const float* cpb_w1 = (const float*)d_in[8];
    const float* cpb_b1 = (const float*)d_in[9];
    const float* cpb_w2 = (const float*)d_in[10];
    const float* proj_w = (const float*)d_in[11];
    const float* proj_b = (const float*)d_in[12];
    const float* n1g    = (const float*)d_in[13];
    const float* n1b    = (const float*)d_in[14];
    const float* n2g    = (const float*)d_in[15];
    const float* n2b    = (const float*)d_in[16];
    const float* fc1_w  = (const float*)d_in[17];
    const float* fc1_b  = (const float*)d_in[18];
    const float* fc2_w  = (const float*)d_in[19];
    const float* fc2_b  = (const float*)d_in[20];
    float* outp = (float*)d_out;

    char* ws = (char*)d_ws;
    const size_t offA    = 0;                       // qkvb(170MB) -> proj_o -> hbuf(226MB)
    const size_t offB    = 226492416;               // attn_o -> t2 (56.6MB)
    const size_t offC    = offB + 56623104;         // xw -> y1b (56.6MB)
    const size_t offBM   = offC + 56623104;         // bm fp32 (15.93MB)
    const size_t offTab  = offBM + 15925248;
    const size_t offQW   = offTab + 25600;
    const size_t offPW   = offQW + 884736;
    const size_t offF1   = offPW + 294912;
    const size_t offF2   = offF1 + 1179648;
    const size_t offQB   = offF2 + 1179648;

    u16*   qkvb    = (u16*)(ws + offA);
    u16*   proj_o  = (u16*)(ws + offA);
    u16*   hbuf    = (u16*)(ws + offA);
    u16*   attn_o  = (u16*)(ws + offB);
    u16*   t2      = (u16*)(ws + offB);
    u16*   xw      = (u16*)(ws + offC);
    u16*   y1b     = (u16*)(ws + offC);
    float* bm      = (float*)(ws + offBM);
    float* tab     = (float*)(ws + offTab);
    u16*   qkv_wT  = (u16*)(ws + offQW);
    u16*   proj_wT = (u16*)(ws + offPW);
    u16*   fc1_wT  = (u16*)(ws + offF1);
    u16*   fc2_wT  = (u16*)(ws + offF2);
    float* qkvbias = (float*)(ws + offQB);

    hipFuncSetAttribute((const void*)&gemm_k<EPI_PLAIN, false, 12>,
                        hipFuncAttributeMaxDynamicSharedMemorySize, 73728);
    hipFuncSetAttribute((const void*)&gemm_k<EPI_GELU, true, 12>,
                        hipFuncAttributeMaxDynamicSharedMemorySize, 73728);
    hipFuncSetAttribute((const void*)&gemm_k<EPI_PLAIN, false, 48>,
                        hipFuncAttributeMaxDynamicSharedMemorySize, 73728);

    wt_convert<<<(384 * 1152 + 255) / 256, 256, 0, stream>>>(qkv_w, qkv_wT, 384, 1152);
    wt_convert<<<(384 * 384 + 255) / 256, 256, 0, stream>>>(proj_w, proj_wT, 384, 384);
    wt_convert<<<(384 * 1536 + 255) / 256, 256, 0, stream>>>(fc1_w, fc1_wT, 384, 1536);
    wt_convert<<<(1536 * 384 + 255) / 256, 256, 0, stream>>>(fc2_w, fc2_wT, 1536, 384);
    build_qkv_bias<<<5, 256, 0, stream>>>(q_bias, v_bias, qkvbias);
    cpb_tab<<<529, 256, 0, stream>>>(table, cpb_w1, cpb_b1, cpb_w2, tab);
    build_bm<<<(12 * 16 * 20736 + 255) / 256, 256, 0, stream>>>(tab, rpi, mask, bm);
    gather_xbf<<<(73728 * 48 + 255) / 256, 256, 0, stream>>>(x, xw);

    gemm_k<EPI_PLAIN, false, 12><<<288 * 9, 256, 73728, stream>>>(xw, qkv_wT, qkvbias, qkvb, 1152, 9);

    attn_k<<<6144, 192, 0, stream>>>(qkvb, bm, lsc, attn_o);

    gemm_k<EPI_PLAIN, false, 12><<<288 * 3, 256, 73728, stream>>>(attn_o, proj_wT, proj_b, proj_o, 384, 3);

    ln1_k<<<18432, 256, 0, stream>>>(proj_o, x, n1g, n1b, y1b);

    gemm_k<EPI_GELU, true, 12><<<288 * 12, 256, 73728, stream>>>(y1b, fc1_wT, fc1_b, hbuf, 1536, 12);

    gemm_k<EPI_PLAIN, false, 48><<<288 * 3, 256, 73728, stream>>>(hbuf, fc2_wT, fc2_b, t2, 384, 3);

    ln2_k<<<18432, 256, 0, stream>>>(t2, y1b, n2g, n2b, outp);
}